// Round 1
// baseline (2991.261 us; speedup 1.0000x reference)
//
#include <hip/hip_runtime.h>
#include <hip/hip_bf16.h>
#include <math.h>

// Problem constants (from reference)
#define BB 2
#define TT 256
#define BT 512      // B*T
#define EE 512
#define GG 8
#define GD 64
#define LL 8
#define NN 64
#define VV 50257
#define D2 32
#define EPS 1.1920928955078125e-07f

typedef __attribute__((ext_vector_type(4))) float floatx4;
typedef __attribute__((ext_vector_type(8))) short short8;

// ---------------- workspace layout (float offsets) ----------------
// live the whole launch:
#define OFF_DEPTHS   0
#define OFF_APS      64
#define OFF_MPS      (OFF_APS + NN*GD)            // 4160
#define OFF_COS      (OFF_MPS + NN*GD)            // 8256
#define OFF_SIN      (OFF_COS + TT*D2)            // 16448
#define OFF_X        (OFF_SIN + TT*D2)            // 24640
#define OFF_PCONT    (OFF_X + BT*EE)              // 286784
#define OFF_SMLP     (OFF_PCONT + BT)             // 287296
// live during the step loop only:
#define OFF_XI       (OFF_SMLP + BT*NN)           // 320064
#define OFF_Q        (OFF_XI + BT*NN*GD)          // 2417216
#define OFF_K        (OFF_Q + BT*NN*GD)           // 4514368
#define OFF_V        (OFF_K + BT*NN*GD)           // 6611520
#define OFF_ATT      (OFF_V + BT*NN*GD)           // 8708672
#define OFF_SCORES   (OFF_ATT + BT*NN*GD)         // 10805824, ends 19194432
// live after the step loop (overlap the dead step buffers):
#define OFF_WBF      OFF_XI                        // bf16, V*E elems = 12,865,792 float-slots
#define OFF_YBF      (OFF_XI + (VV*EE)/2)          // 13185856, bf16, BT*E elems
// total ws floats: 19,194,432  (~76.8 MB)

__device__ __forceinline__ float step_weight(const float* depths, const int* ns, int t, int n) {
    float td = (float)t * (8.0f / (float)ns[0]);
    float wa = expf(-fabsf(depths[n] - td));
    return (wa > 0.15f) ? wa : 0.0f;
}

// depths = iterate depths = relu(dep) @ (depths+1), L times.  1 block, 64 threads.
__global__ void k_prep(const float* __restrict__ dep, float* __restrict__ depths) {
    __shared__ float cur[NN], nxt[NN];
    int i = threadIdx.x;
    if (i < NN) cur[i] = 0.f;
    __syncthreads();
    for (int it = 0; it < LL; ++it) {
        if (i < NN) {
            float acc = 0.f;
            for (int m = 0; m < NN; ++m) acc += fmaxf(dep[i*NN + m], 0.f) * (cur[m] + 1.f);
            nxt[i] = acc;
        }
        __syncthreads();
        if (i < NN) cur[i] = nxt[i];
        __syncthreads();
    }
    if (i < NN) depths[i] = cur[i];
}

// aps[n,g] = sum_k attn_proj[n,g,k];  mps[n,g] = sum_k mlp_proj[n,g,k]
__global__ void k_sums(const float* __restrict__ attn_proj, const float* __restrict__ mlp_proj,
                       float* __restrict__ aps, float* __restrict__ mps) {
    int i = blockIdx.x * blockDim.x + threadIdx.x;
    if (i >= NN*GD) return;
    float a = 0.f;
    const float* ap = attn_proj + (size_t)i * GD;
    for (int k = 0; k < GD; ++k) a += ap[k];
    aps[i] = a;
    float m = 0.f;
    const float* mp = mlp_proj + (size_t)i * 4 * GD;
    for (int k = 0; k < 4*GD; ++k) m += mp[k];
    mps[i] = m;
}

// rope tables in double (matches numpy float64 then cast to f32)
__global__ void k_rope_table(float* __restrict__ ctab, float* __restrict__ stab) {
    int i = blockIdx.x * blockDim.x + threadIdx.x;
    if (i >= TT*D2) return;
    int pos = i / D2, f = i % D2;
    double inv = pow(10000.0, -((double)(2*f)) / (double)GD);
    double ang = (double)pos * inv;
    ctab[i] = (float)cos(ang);
    stab[i] = (float)sin(ang);
}

// x = rms(wte[idx]); p_cont = 1.  One block per token, 256 threads.
__global__ void k_embed(const int* __restrict__ idx, const float* __restrict__ wte,
                        float* __restrict__ x, float* __restrict__ pcont) {
    int bt = blockIdx.x;
    int tid = threadIdx.x;
    const float* src = wte + (size_t)idx[bt] * EE;
    float v0 = src[tid], v1 = src[tid + 256];
    __shared__ float red[4];
    float ss = v0*v0 + v1*v1;
    for (int o = 32; o > 0; o >>= 1) ss += __shfl_xor(ss, o);
    if ((tid & 63) == 0) red[tid >> 6] = ss;
    __syncthreads();
    float sc = rsqrtf((red[0]+red[1]+red[2]+red[3]) / (float)EE + EPS);
    x[bt*EE + tid]       = v0 * sc;
    x[bt*EE + tid + 256] = v1 * sc;
    if (tid == 0) pcont[bt] = 1.f;
}

// xi[bt,n,g] = adapters[n] @ x[bt] + x[bt, (n%8)*64 + g].  grid (BT/64, NN), 256 thr.
__global__ __launch_bounds__(256) void k_xi(const float* __restrict__ x, const float* __restrict__ adapters,
                                            float* __restrict__ xi, const float* __restrict__ depths,
                                            const int* __restrict__ ns, int t) {
    int n = blockIdx.y;
    if (step_weight(depths, ns, t, n) == 0.f) return;
    int bt0 = blockIdx.x * 64;
    __shared__ float xs[64][33];
    __shared__ float as[64][33];
    int tid = threadIdx.x;
    int ty = tid >> 4, tx = tid & 15;
    float acc[4][4] = {};
    for (int e0 = 0; e0 < EE; e0 += 32) {
        for (int i = tid; i < 64*32; i += 256) {
            int r = i >> 5, c = i & 31;
            xs[r][c] = x[(bt0 + r)*EE + e0 + c];
            as[r][c] = adapters[((size_t)n*GD + r)*EE + e0 + c];
        }
        __syncthreads();
        for (int kk = 0; kk < 32; ++kk) {
            float av[4], bv[4];
            #pragma unroll
            for (int i = 0; i < 4; ++i) av[i] = xs[ty*4 + i][kk];
            #pragma unroll
            for (int j = 0; j < 4; ++j) bv[j] = as[tx*4 + j][kk];
            #pragma unroll
            for (int i = 0; i < 4; ++i)
                #pragma unroll
                for (int j = 0; j < 4; ++j) acc[i][j] += av[i] * bv[j];
        }
        __syncthreads();
    }
    int gofs = (n & (GG-1)) * GD;
    #pragma unroll
    for (int i = 0; i < 4; ++i) {
        int r = bt0 + ty*4 + i;
        #pragma unroll
        for (int j = 0; j < 4; ++j) {
            int c = tx*4 + j;
            xi[((size_t)r*NN + n)*GD + c] = acc[i][j] + x[r*EE + gofs + c];
        }
    }
}

// qkv = qkv_w[n] @ xi[bt,n].  grid (BT/64, NN), 256 thr.
__global__ __launch_bounds__(256) void k_qkv(const float* __restrict__ xi, const float* __restrict__ qkv_w,
                                             float* __restrict__ q, float* __restrict__ k, float* __restrict__ v,
                                             const float* __restrict__ depths, const int* __restrict__ ns, int t) {
    int n = blockIdx.y;
    if (step_weight(depths, ns, t, n) == 0.f) return;
    int bt0 = blockIdx.x * 64;
    __shared__ float xin[64][65];
    int tid = threadIdx.x;
    for (int i = tid; i < 64*64; i += 256) {
        int r = i >> 6, g = i & 63;
        xin[r][g] = xi[((size_t)(bt0 + r)*NN + n)*GD + g];
    }
    __syncthreads();
    const float* w = qkv_w + (size_t)n * 192 * GD;
    for (int oi = tid; oi < 64*192; oi += 256) {
        int r = oi / 192, o = oi % 192;
        const float* wr = w + o*GD;
        float acc = 0.f;
        for (int g = 0; g < GD; ++g) acc += wr[g] * xin[r][g];
        int bt = bt0 + r;
        float* dst = (o < 64) ? q : ((o < 128) ? k : v);
        dst[((size_t)bt*NN + n)*GD + (o & 63)] = acc;
    }
}

// rope + rms on q and k, one wave per (bt,n,row).  grid 2*BT*NN/4 blocks of 256.
__global__ void k_ropenorm(float* __restrict__ q, float* __restrict__ k,
                           const float* __restrict__ ctab, const float* __restrict__ stab,
                           const float* __restrict__ depths, const int* __restrict__ ns, int t) {
    int gid = blockIdx.x * 4 + (threadIdx.x >> 6);
    int lane = threadIdx.x & 63;
    int which = gid >> 15;          // BT*NN = 32768
    int rowid = gid & 32767;
    int n = rowid & 63;
    if (step_weight(depths, ns, t, n) == 0.f) return;
    int bt = rowid >> 6;
    int pos = bt & (TT - 1);
    float* ptr = (which ? k : q) + (size_t)rowid * GD;
    float val = ptr[lane];
    float other = __shfl_xor(val, 32);
    int fi = (lane < D2) ? lane : (lane - D2);
    float c = ctab[pos*D2 + fi], s = stab[pos*D2 + fi];
    float nv = (lane < D2) ? (val*c + other*s) : (-other*s + val*c);
    float ss = nv*nv;
    for (int o = 32; o > 0; o >>= 1) ss += __shfl_xor(ss, o);
    float sc = rsqrtf(ss / (float)GD + EPS);
    ptr[lane] = nv * sc;
}

// scores tile (64x64), causal tiles only.  grid (4,4,B*NN)
__global__ __launch_bounds__(256) void k_scores(const float* __restrict__ q, const float* __restrict__ k,
                                                float* __restrict__ scores,
                                                const float* __restrict__ depths, const int* __restrict__ ns, int t) {
    int it = blockIdx.x, jt = blockIdx.y;
    if (jt > it) return;
    int bn = blockIdx.z;
    int b = bn >> 6, n = bn & 63;
    if (step_weight(depths, ns, t, n) == 0.f) return;
    __shared__ float qs[64][65], ks[64][65];
    int tid = threadIdx.x;
    for (int i = tid; i < 4096; i += 256) {
        int r = i >> 6, g = i & 63;
        qs[r][g] = q[(((size_t)b*TT + it*64 + r)*NN + n)*GD + g];
        ks[r][g] = k[(((size_t)b*TT + jt*64 + r)*NN + n)*GD + g];
    }
    __syncthreads();
    int ty = tid >> 4, tx = tid & 15;
    float acc[4][4] = {};
    for (int kk = 0; kk < 64; ++kk) {
        float av[4], bv[4];
        #pragma unroll
        for (int i = 0; i < 4; ++i) av[i] = qs[ty*4 + i][kk];
        #pragma unroll
        for (int j = 0; j < 4; ++j) bv[j] = ks[tx*4 + j][kk];
        #pragma unroll
        for (int i = 0; i < 4; ++i)
            #pragma unroll
            for (int j = 0; j < 4; ++j) acc[i][j] += av[i] * bv[j];
    }
    const float scale = 0.125f;   // 1/sqrt(64)
    #pragma unroll
    for (int i = 0; i < 4; ++i) {
        int tq = it*64 + ty*4 + i;
        #pragma unroll
        for (int j = 0; j < 4; ++j) {
            int ts = jt*64 + tx*4 + j;
            scores[((size_t)bn*TT + tq)*TT + ts] = (ts <= tq) ? acc[i][j]*scale : -1e30f;
        }
    }
}

// softmax over ts, one wave per row.  grid B*NN*TT/4
__global__ void k_softmax(float* __restrict__ scores,
                          const float* __restrict__ depths, const int* __restrict__ ns, int t) {
    int row = blockIdx.x * 4 + (threadIdx.x >> 6);   // (bn)*256 + tq
    int lane = threadIdx.x & 63;
    int n = (row >> 8) & 63;
    if (step_weight(depths, ns, t, n) == 0.f) return;
    int tq = row & 255;
    float* p = scores + (size_t)row * TT;
    float v[4];
    float mx = -1e30f;
    #pragma unroll
    for (int j = 0; j < 4; ++j) {
        int ts = lane + j*64;
        v[j] = (ts <= tq) ? p[ts] : -1e30f;
        mx = fmaxf(mx, v[j]);
    }
    for (int o = 32; o > 0; o >>= 1) mx = fmaxf(mx, __shfl_xor(mx, o));
    float sum = 0.f;
    #pragma unroll
    for (int j = 0; j < 4; ++j) {
        int ts = lane + j*64;
        v[j] = (ts <= tq) ? expf(v[j] - mx) : 0.f;
        sum += v[j];
    }
    for (int o = 32; o > 0; o >>= 1) sum += __shfl_xor(sum, o);
    float inv = 1.f / sum;
    #pragma unroll
    for (int j = 0; j < 4; ++j) p[lane + j*64] = v[j] * inv;
}

// att = P @ V per (bn, tq-tile).  grid (4, B*NN)
__global__ __launch_bounds__(256) void k_att(const float* __restrict__ scores, const float* __restrict__ v,
                                             float* __restrict__ att,
                                             const float* __restrict__ depths, const int* __restrict__ ns, int t) {
    int it = blockIdx.x;
    int bn = blockIdx.y;
    int b = bn >> 6, n = bn & 63;
    if (step_weight(depths, ns, t, n) == 0.f) return;
    __shared__ float ps[64][65], vs[64][65];
    int tid = threadIdx.x, ty = tid >> 4, tx = tid & 15;
    float acc[4][4] = {};
    for (int ct = 0; ct <= it; ++ct) {
        for (int i = tid; i < 4096; i += 256) {
            int r = i >> 6, c = i & 63;
            ps[r][c] = scores[((size_t)bn*TT + it*64 + r)*TT + ct*64 + c];
            vs[r][c] = v[(((size_t)b*TT + ct*64 + r)*NN + n)*GD + c];
        }
        __syncthreads();
        for (int kk = 0; kk < 64; ++kk) {
            float av[4], bv[4];
            #pragma unroll
            for (int i = 0; i < 4; ++i) av[i] = ps[ty*4 + i][kk];
            #pragma unroll
            for (int j = 0; j < 4; ++j) bv[j] = vs[kk][tx*4 + j];
            #pragma unroll
            for (int i = 0; i < 4; ++i)
                #pragma unroll
                for (int j = 0; j < 4; ++j) acc[i][j] += av[i] * bv[j];
        }
        __syncthreads();
    }
    #pragma unroll
    for (int i = 0; i < 4; ++i) {
        int bt = b*TT + it*64 + ty*4 + i;
        #pragma unroll
        for (int j = 0; j < 4; ++j)
            att[((size_t)bt*NN + n)*GD + tx*4 + j] = acc[i][j];
    }
}

// s_mlp[bt,n] = sum_o relu(mlp_fc[n] @ rms(xi + att*aps))^2.  grid (BT, NN), 256 thr.
__global__ __launch_bounds__(256) void k_fc(const float* __restrict__ xi, const float* __restrict__ att,
                                            const float* __restrict__ aps, const float* __restrict__ mlp_fc,
                                            float* __restrict__ smlp,
                                            const float* __restrict__ depths, const int* __restrict__ ns, int t) {
    int bt = blockIdx.x, n = blockIdx.y;
    if (step_weight(depths, ns, t, n) == 0.f) return;
    __shared__ float ym[64];
    __shared__ float sscale;
    __shared__ float red[4];
    int tid = threadIdx.x;
    if (tid < 64) {
        size_t base = ((size_t)bt*NN + n)*GD + tid;
        float xv = xi[base] + att[base] * aps[n*GD + tid];
        ym[tid] = xv;
        float ss = xv*xv;
        for (int o = 32; o > 0; o >>= 1) ss += __shfl_xor(ss, o);
        if (tid == 0) sscale = rsqrtf(ss / (float)GD + EPS);
    }
    __syncthreads();
    const float* w = mlp_fc + ((size_t)n*256 + tid)*GD;
    float acc = 0.f;
    for (int g = 0; g < GD; ++g) acc += w[g] * ym[g];
    acc *= sscale;
    float r = fmaxf(acc, 0.f);
    r = r*r;
    for (int o = 32; o > 0; o >>= 1) r += __shfl_xor(r, o);
    if ((tid & 63) == 0) red[tid >> 6] = r;
    __syncthreads();
    if (tid == 0) smlp[bt*NN + n] = red[0]+red[1]+red[2]+red[3];
}

// x += p_cont * sum_l w_eff*(att*aps + s*mps); then router update.  grid BT, 256 thr.
__global__ __launch_bounds__(256) void k_update(float* __restrict__ x, float* __restrict__ pcont,
                                                const float* __restrict__ att, const float* __restrict__ smlp,
                                                const float* __restrict__ aps, const float* __restrict__ mps,
                                                const float* __restrict__ router_w, const float* __restrict__ router_b,
                                                const float* __restrict__ depths, const int* __restrict__ ns, int t) {
    int bt = blockIdx.x, tid = threadIdx.x;
    __shared__ float we[NN];
    __shared__ float red[4];
    if (tid < NN) we[tid] = step_weight(depths, ns, t, tid);
    __syncthreads();
    float pc = pcont[bt];
    float dot = 0.f;
    #pragma unroll
    for (int h = 0; h < 2; ++h) {
        int e = tid + h*256;
        int gq = e >> 6, gd = e & 63;
        float sum = 0.f;
        #pragma unroll
        for (int l = 0; l < LL; ++l) {
            int n = l*GG + gq;
            float w = we[n];
            if (w != 0.f) {
                sum += (att[((size_t)bt*NN + n)*GD + gd] * aps[n*GD + gd]
                        + smlp[bt*NN + n] * mps[n*GD + gd]) * w;
            }
        }
        float xv = x[bt*EE + e] + sum * pc;
        x[bt*EE + e] = xv;
        dot += xv * router_w[e];
    }
    for (int o = 32; o > 0; o >>= 1) dot += __shfl_xor(dot, o);
    if ((tid & 63) == 0) red[tid >> 6] = dot;
    __syncthreads();
    if (tid == 0) {
        float z = red[0]+red[1]+red[2]+red[3] + router_b[0];
        float ph = 1.f / (1.f + expf(-z));
        pcont[bt] = pc * (1.f - ph);
    }
}

// y = bf16(rms(x)).  grid BT, 256 thr.
__global__ void k_rmsconv(const float* __restrict__ x, __hip_bfloat16* __restrict__ ybf) {
    int bt = blockIdx.x, tid = threadIdx.x;
    float v0 = x[bt*EE + tid], v1 = x[bt*EE + tid + 256];
    __shared__ float red[4];
    float ss = v0*v0 + v1*v1;
    for (int o = 32; o > 0; o >>= 1) ss += __shfl_xor(ss, o);
    if ((tid & 63) == 0) red[tid >> 6] = ss;
    __syncthreads();
    float sc = rsqrtf((red[0]+red[1]+red[2]+red[3]) / (float)EE + EPS);
    ybf[bt*EE + tid]       = __float2bfloat16(v0 * sc);
    ybf[bt*EE + tid + 256] = __float2bfloat16(v1 * sc);
}

// wbf = bf16(lm_head_w)
__global__ void k_convw(const float* __restrict__ w, __hip_bfloat16* __restrict__ wbf) {
    size_t i = ((size_t)blockIdx.x * blockDim.x + threadIdx.x) * 4;
    if (i >= (size_t)VV*EE) return;
    float4 f = *(const float4*)(w + i);
    wbf[i+0] = __float2bfloat16(f.x);
    wbf[i+1] = __float2bfloat16(f.y);
    wbf[i+2] = __float2bfloat16(f.z);
    wbf[i+3] = __float2bfloat16(f.w);
}

// out = 15*tanh((rms(x) @ W^T)/15), bf16 MFMA 16x16x32.  grid (4, ceil(V/128)), 256 thr (4 waves).
#define LM_BK 32
#define LM_PAD 48   // bf16 elems per LDS row (96 B, 16B-aligned rows)
__global__ __launch_bounds__(256) void k_lmhead(const __hip_bfloat16* __restrict__ ybf,
                                                const __hip_bfloat16* __restrict__ wbf,
                                                float* __restrict__ out) {
    __shared__ __align__(16) __hip_bfloat16 As[128][LM_PAD];
    __shared__ __align__(16) __hip_bfloat16 Bs[128][LM_PAD];
    int tid = threadIdx.x;
    int wave = tid >> 6, lane = tid & 63;
    int wr = wave >> 1, wc = wave & 1;
    int quad = lane >> 4, l16 = lane & 15;
    int bm = blockIdx.x, bn = blockIdx.y;
    floatx4 acc[4][4];
    #pragma unroll
    for (int mt = 0; mt < 4; ++mt)
        #pragma unroll
        for (int nt = 0; nt < 4; ++nt)
            acc[mt][nt] = (floatx4){0.f, 0.f, 0.f, 0.f};

    for (int k0 = 0; k0 < EE; k0 += LM_BK) {
        // stage A: 128 rows x 32 k (4096 bf16 = 512 x 16B chunks)
        for (int c = tid; c < 512; c += 256) {
            int row = c >> 2, koff = (c & 3) * 8;
            uint4 val = *(const uint4*)(ybf + ((size_t)(bm*128 + row)*EE + k0 + koff));
            *(uint4*)(&As[row][koff]) = val;
        }
        // stage B: 128 vocab rows x 32 k
        for (int c = tid; c < 512; c += 256) {
            int row = c >> 2, koff = (c & 3) * 8;
            int vrow = bn*128 + row;
            if (vrow >= VV) vrow = VV - 1;
            uint4 val = *(const uint4*)(wbf + ((size_t)vrow*EE + k0 + koff));
            *(uint4*)(&Bs[row][koff]) = val;
        }
        __syncthreads();
        short8 af[4], bf[4];
        #pragma unroll
        for (int mt = 0; mt < 4; ++mt)
            af[mt] = *(const short8*)(&As[wr*64 + mt*16 + l16][quad*8]);
        #pragma unroll
        for (int nt = 0; nt < 4; ++nt)
            bf[nt] = *(const short8*)(&Bs[wc*64 + nt*16 + l16][quad*8]);
        #pragma unroll
        for (int mt = 0; mt < 4; ++mt)
            #pragma unroll
            for (int nt = 0; nt < 4; ++nt)
                acc[mt][nt] = __builtin_amdgcn_mfma_f32_16x16x32_bf16(af[mt], bf[nt], acc[mt][nt], 0, 0, 0);
        __syncthreads();
    }
    #pragma unroll
    for (int mt = 0; mt < 4; ++mt) {
        int gm = bm*128 + wr*64 + mt*16 + quad*4;
        #pragma unroll
        for (int nt = 0; nt < 4; ++nt) {
            int gn = bn*128 + wc*64 + nt*16 + l16;
            if (gn < VV) {
                #pragma unroll
                for (int r = 0; r < 4; ++r) {
                    float lv = acc[mt][nt][r];
                    out[(size_t)(gm + r)*VV + gn] = 15.f * tanhf(lv * (1.f/15.f));
                }
            }
        }
    }
}

extern "C" void kernel_launch(void* const* d_in, const int* in_sizes, int n_in,
                              void* d_out, int out_size, void* d_ws, size_t ws_size,
                              hipStream_t stream) {
    (void)in_sizes; (void)n_in; (void)out_size; (void)ws_size;
    const int*   idx       = (const int*)d_in[0];
    const int*   nsteps    = (const int*)d_in[1];
    const float* wte       = (const float*)d_in[2];
    const float* adapters  = (const float*)d_in[3];
    const float* qkv_w     = (const float*)d_in[4];
    const float* attn_proj = (const float*)d_in[5];
    const float* mlp_fc    = (const float*)d_in[6];
    const float* mlp_proj  = (const float*)d_in[7];
    const float* dep       = (const float*)d_in[8];
    const float* router_w  = (const float*)d_in[9];
    const float* router_b  = (const float*)d_in[10];
    const float* lm_head   = (const float*)d_in[11];
    float* out = (float*)d_out;
    float* ws  = (float*)d_ws;

    float* depths = ws + OFF_DEPTHS;
    float* aps    = ws + OFF_APS;
    float* mps    = ws + OFF_MPS;
    float* ctab   = ws + OFF_COS;
    float* stab   = ws + OFF_SIN;
    float* x      = ws + OFF_X;
    float* pcont  = ws + OFF_PCONT;
    float* smlp   = ws + OFF_SMLP;
    float* xi     = ws + OFF_XI;
    float* q      = ws + OFF_Q;
    float* k      = ws + OFF_K;
    float* v      = ws + OFF_V;
    float* att    = ws + OFF_ATT;
    float* scores = ws + OFF_SCORES;
    __hip_bfloat16* wbf = (__hip_bfloat16*)(ws + OFF_WBF);
    __hip_bfloat16* ybf = (__hip_bfloat16*)(ws + OFF_YBF);

    k_prep<<<1, 64, 0, stream>>>(dep, depths);
    k_sums<<<(NN*GD + 255)/256, 256, 0, stream>>>(attn_proj, mlp_proj, aps, mps);
    k_rope_table<<<(TT*D2 + 255)/256, 256, 0, stream>>>(ctab, stab);
    k_embed<<<BT, 256, 0, stream>>>(idx, wte, x, pcont);

    for (int t = 0; t < 8; ++t) {
        k_xi<<<dim3(BT/64, NN), 256, 0, stream>>>(x, adapters, xi, depths, nsteps, t);
        k_qkv<<<dim3(BT/64, NN), 256, 0, stream>>>(xi, qkv_w, q, k, v, depths, nsteps, t);
        k_ropenorm<<<(2*BT*NN)/4/1, 256, 0, stream>>>(q, k, ctab, stab, depths, nsteps, t);
        k_scores<<<dim3(4, 4, BB*NN), 256, 0, stream>>>(q, k, scores, depths, nsteps, t);
        k_softmax<<<(BB*NN*TT)/4, 256, 0, stream>>>(scores, depths, nsteps, t);
        k_att<<<dim3(4, BB*NN), 256, 0, stream>>>(scores, v, att, depths, nsteps, t);
        k_fc<<<dim3(BT, NN), 256, 0, stream>>>(xi, att, aps, mlp_fc, smlp, depths, nsteps, t);
        k_update<<<BT, 256, 0, stream>>>(x, pcont, att, smlp, aps, mps, router_w, router_b, depths, nsteps, t);
    }

    k_rmsconv<<<BT, 256, 0, stream>>>(x, ybf);
    k_convw<<<((VV*EE)/4 + 255)/256, 256, 0, stream>>>(lm_head, wbf);
    k_lmhead<<<dim3(BT/128, (VV + 127)/128), 256, 0, stream>>>(ybf, wbf, out);
}

// Round 2
// 2314.507 us; speedup vs baseline: 1.2924x; 1.2924x over previous
//
#include <hip/hip_runtime.h>
#include <hip/hip_bf16.h>
#include <math.h>

// Problem constants (from reference)
#define BB 2
#define TT 256
#define BT 512      // B*T
#define EE 512
#define GG 8
#define GD 64
#define LL 8
#define NN 64
#define VV 50257
#define D2 32
#define EPS 1.1920928955078125e-07f

typedef __attribute__((ext_vector_type(4))) float floatx4;
typedef __attribute__((ext_vector_type(8))) short short8;

// ---------------- workspace layout (float offsets) ----------------
#define OFF_DEPTHS   0
#define OFF_APS      64
#define OFF_MPS      (OFF_APS + NN*GD)
#define OFF_COS      (OFF_MPS + NN*GD)
#define OFF_SIN      (OFF_COS + TT*D2)
#define OFF_X        (OFF_SIN + TT*D2)
#define OFF_PCONT    (OFF_X + BT*EE)
#define OFF_SMLP     (OFF_PCONT + BT)
#define OFF_XI       (OFF_SMLP + BT*NN)
#define OFF_Q        (OFF_XI + BT*NN*GD)
#define OFF_K        (OFF_Q + BT*NN*GD)
#define OFF_V        (OFF_K + BT*NN*GD)
#define OFF_ATT      (OFF_V + BT*NN*GD)
// bf16 buffers overlap the region after ATT (old scores region)
#define OFF_WBF      (OFF_ATT + BT*NN*GD)
#define OFF_YBF      (OFF_WBF + (VV*EE)/2)

__device__ __forceinline__ float step_weight(const float* depths, const int* ns, int t, int n) {
    float td = (float)t * (8.0f / (float)ns[0]);
    float wa = expf(-fabsf(depths[n] - td));
    return (wa > 0.15f) ? wa : 0.0f;
}

__global__ void k_prep(const float* __restrict__ dep, float* __restrict__ depths) {
    __shared__ float cur[NN], nxt[NN];
    int i = threadIdx.x;
    if (i < NN) cur[i] = 0.f;
    __syncthreads();
    for (int it = 0; it < LL; ++it) {
        if (i < NN) {
            float acc = 0.f;
            for (int m = 0; m < NN; ++m) acc += fmaxf(dep[i*NN + m], 0.f) * (cur[m] + 1.f);
            nxt[i] = acc;
        }
        __syncthreads();
        if (i < NN) cur[i] = nxt[i];
        __syncthreads();
    }
    if (i < NN) depths[i] = cur[i];
}

__global__ void k_sums(const float* __restrict__ attn_proj, const float* __restrict__ mlp_proj,
                       float* __restrict__ aps, float* __restrict__ mps) {
    int i = blockIdx.x * blockDim.x + threadIdx.x;
    if (i >= NN*GD) return;
    float a = 0.f;
    const float* ap = attn_proj + (size_t)i * GD;
    for (int k = 0; k < GD; ++k) a += ap[k];
    aps[i] = a;
    float m = 0.f;
    const float* mp = mlp_proj + (size_t)i * 4 * GD;
    for (int k = 0; k < 4*GD; ++k) m += mp[k];
    mps[i] = m;
}

__global__ void k_rope_table(float* __restrict__ ctab, float* __restrict__ stab) {
    int i = blockIdx.x * blockDim.x + threadIdx.x;
    if (i >= TT*D2) return;
    int pos = i / D2, f = i % D2;
    double inv = pow(10000.0, -((double)(2*f)) / (double)GD);
    double ang = (double)pos * inv;
    ctab[i] = (float)cos(ang);
    stab[i] = (float)sin(ang);
}

__global__ void k_embed(const int* __restrict__ idx, const float* __restrict__ wte,
                        float* __restrict__ x, float* __restrict__ pcont) {
    int bt = blockIdx.x;
    int tid = threadIdx.x;
    const float* src = wte + (size_t)idx[bt] * EE;
    float v0 = src[tid], v1 = src[tid + 256];
    __shared__ float red[4];
    float ss = v0*v0 + v1*v1;
    for (int o = 32; o > 0; o >>= 1) ss += __shfl_xor(ss, o);
    if ((tid & 63) == 0) red[tid >> 6] = ss;
    __syncthreads();
    float sc = rsqrtf((red[0]+red[1]+red[2]+red[3]) / (float)EE + EPS);
    x[bt*EE + tid]       = v0 * sc;
    x[bt*EE + tid + 256] = v1 * sc;
    if (tid == 0) pcont[bt] = 1.f;
}

// ---- Fused xi + qkv + rope + rms.  grid (BT/64, NN), 256 thr. ----
__global__ __launch_bounds__(256) void k_xi_qkv(const float* __restrict__ x, const float* __restrict__ adapters,
        const float* __restrict__ qkv_w, float* __restrict__ xi,
        float* __restrict__ q, float* __restrict__ k, float* __restrict__ v,
        const float* __restrict__ ctab, const float* __restrict__ stab,
        const float* __restrict__ depths, const int* __restrict__ ns, int t) {
    int n = blockIdx.y;
    if (step_weight(depths, ns, t, n) == 0.f) return;
    int bt0 = blockIdx.x * 64;
    __shared__ float lds[4160 + 8320];   // xis[64*65] + union region
    float* xis = lds;
    float* r2  = lds + 4160;
    int tid = threadIdx.x;
    int ty = tid >> 4, tx = tid & 15;

    // ---- phase 1: xi = adapters[n] @ x (64x64 over K=512) ----
    float* xs  = r2;           // [64][33]
    float* as_ = r2 + 2112;    // [64][33]
    float acc[4][4] = {};
    for (int e0 = 0; e0 < EE; e0 += 32) {
        for (int i4 = tid; i4 < 512; i4 += 256) {
            int r = i4 >> 3, c4 = (i4 & 7) * 4;
            float4 fx = *(const float4*)(x + (size_t)(bt0 + r)*EE + e0 + c4);
            float4 fa = *(const float4*)(adapters + ((size_t)n*GD + r)*EE + e0 + c4);
            xs[r*33 + c4+0] = fx.x; xs[r*33 + c4+1] = fx.y; xs[r*33 + c4+2] = fx.z; xs[r*33 + c4+3] = fx.w;
            as_[r*33 + c4+0] = fa.x; as_[r*33 + c4+1] = fa.y; as_[r*33 + c4+2] = fa.z; as_[r*33 + c4+3] = fa.w;
        }
        __syncthreads();
        for (int kk = 0; kk < 32; ++kk) {
            float av[4], bv[4];
            #pragma unroll
            for (int i = 0; i < 4; ++i) av[i] = xs[(ty*4 + i)*33 + kk];
            #pragma unroll
            for (int j = 0; j < 4; ++j) bv[j] = as_[(tx*4 + j)*33 + kk];
            #pragma unroll
            for (int i = 0; i < 4; ++i)
                #pragma unroll
                for (int j = 0; j < 4; ++j) acc[i][j] += av[i] * bv[j];
        }
        __syncthreads();
    }
    int gofs = (n & (GG-1)) * GD;
    #pragma unroll
    for (int i = 0; i < 4; ++i) {
        int r = ty*4 + i, bt = bt0 + r;
        #pragma unroll
        for (int j = 0; j < 4; ++j) {
            int c = tx*4 + j;
            float val = acc[i][j] + x[(size_t)bt*EE + gofs + c];
            xi[((size_t)bt*NN + n)*GD + c] = val;
            xis[r*65 + c] = val;
        }
    }
    __syncthreads();

    // ---- phase 2: qkv = xis @ qkv_w[n]^T, then rope+rms on q,k ----
    float* wbuf = r2;           // [64][65]
    float* obuf = r2 + 4160;    // [64][65]
    int lane = tid & 63, wv = tid >> 6;
    const float* wbase = qkv_w + (size_t)n * 192 * GD;
    for (int c = 0; c < 3; ++c) {
        for (int i4 = tid; i4 < 1024; i4 += 256) {
            int oo = i4 >> 4, c4 = (i4 & 15) * 4;
            float4 f = *(const float4*)(wbase + (size_t)(c*64 + oo)*GD + c4);
            wbuf[oo*65 + c4+0] = f.x; wbuf[oo*65 + c4+1] = f.y;
            wbuf[oo*65 + c4+2] = f.z; wbuf[oo*65 + c4+3] = f.w;
        }
        __syncthreads();
        {
            int r = lane;
            for (int j = 0; j < 16; ++j) {
                int oo = wv*16 + j;
                float a = 0.f;
                for (int g = 0; g < 64; ++g) a += xis[r*65 + g] * wbuf[oo*65 + g];
                obuf[r*65 + oo] = a;
            }
        }
        __syncthreads();
        float* dst = (c == 0) ? q : ((c == 1) ? k : v);
        for (int tr = 0; tr < 16; ++tr) {
            int row = wv*16 + tr, bt = bt0 + row;
            float val = obuf[row*65 + lane];
            if (c < 2) {
                int pos = bt & (TT - 1);
                float pair = __shfl_xor(val, 32);
                int fi = lane & 31;
                float cc = ctab[pos*D2 + fi], sn = stab[pos*D2 + fi];
                float nv = (lane < 32) ? (val*cc + pair*sn) : (val*cc - pair*sn);
                float ss = nv*nv;
                for (int o = 32; o > 0; o >>= 1) ss += __shfl_xor(ss, o);
                val = nv * rsqrtf(ss / (float)GD + EPS);
            }
            dst[((size_t)bt*NN + n)*GD + lane] = val;
        }
        __syncthreads();
    }
}

// ---- Flash attention per (tq-tile, b, n).  grid (4, B, NN), 256 thr. ----
__global__ __launch_bounds__(256) void k_attn(const float* __restrict__ q, const float* __restrict__ k,
        const float* __restrict__ v, float* __restrict__ att,
        const float* __restrict__ depths, const int* __restrict__ ns, int t) {
    int it = blockIdx.x, b = blockIdx.y, n = blockIdx.z;
    if (step_weight(depths, ns, t, n) == 0.f) return;
    __shared__ float qs[64*65], ks[64*65], vs[64*65], ps[64*65];
    int tid = threadIdx.x, ty = tid >> 4, tx = tid & 15;
    for (int i4 = tid; i4 < 1024; i4 += 256) {
        int r = i4 >> 4, c4 = (i4 & 15) * 4;
        float4 f = *(const float4*)(q + (((size_t)(b*TT + it*64 + r))*NN + n)*GD + c4);
        qs[r*65 + c4+0] = f.x; qs[r*65 + c4+1] = f.y; qs[r*65 + c4+2] = f.z; qs[r*65 + c4+3] = f.w;
    }
    float m_i[4], l_i[4], acc[4][4];
    #pragma unroll
    for (int i = 0; i < 4; ++i) {
        m_i[i] = -INFINITY; l_i[i] = 0.f;
        #pragma unroll
        for (int j = 0; j < 4; ++j) acc[i][j] = 0.f;
    }
    __syncthreads();
    for (int ct = 0; ct <= it; ++ct) {
        for (int i4 = tid; i4 < 1024; i4 += 256) {
            int r = i4 >> 4, c4 = (i4 & 15) * 4;
            size_t base = (((size_t)(b*TT + ct*64 + r))*NN + n)*GD + c4;
            float4 fk = *(const float4*)(k + base);
            float4 fv = *(const float4*)(v + base);
            ks[r*65 + c4+0] = fk.x; ks[r*65 + c4+1] = fk.y; ks[r*65 + c4+2] = fk.z; ks[r*65 + c4+3] = fk.w;
            vs[r*65 + c4+0] = fv.x; vs[r*65 + c4+1] = fv.y; vs[r*65 + c4+2] = fv.z; vs[r*65 + c4+3] = fv.w;
        }
        __syncthreads();
        float s[4][4] = {};
        for (int kk = 0; kk < 64; ++kk) {
            float av[4], bv[4];
            #pragma unroll
            for (int i = 0; i < 4; ++i) av[i] = qs[(ty*4 + i)*65 + kk];
            #pragma unroll
            for (int j = 0; j < 4; ++j) bv[j] = ks[(tx*4 + j)*65 + kk];
            #pragma unroll
            for (int i = 0; i < 4; ++i)
                #pragma unroll
                for (int j = 0; j < 4; ++j) s[i][j] += av[i] * bv[j];
        }
        #pragma unroll
        for (int i = 0; i < 4; ++i) {
            int row = it*64 + ty*4 + i;
            #pragma unroll
            for (int j = 0; j < 4; ++j) {
                int col = ct*64 + tx*4 + j;
                s[i][j] = (col <= row) ? s[i][j] * 0.125f : -INFINITY;
            }
        }
        #pragma unroll
        for (int i = 0; i < 4; ++i) {
            float mx = fmaxf(fmaxf(s[i][0], s[i][1]), fmaxf(s[i][2], s[i][3]));
            for (int o = 8; o > 0; o >>= 1) mx = fmaxf(mx, __shfl_xor(mx, o));
            float mnew = fmaxf(m_i[i], mx);
            float alpha = expf(m_i[i] - mnew);
            float rs = 0.f;
            #pragma unroll
            for (int j = 0; j < 4; ++j) { float p = expf(s[i][j] - mnew); s[i][j] = p; rs += p; }
            for (int o = 8; o > 0; o >>= 1) rs += __shfl_xor(rs, o);
            l_i[i] = l_i[i]*alpha + rs;
            m_i[i] = mnew;
            #pragma unroll
            for (int jj = 0; jj < 4; ++jj) acc[i][jj] *= alpha;
        }
        #pragma unroll
        for (int i = 0; i < 4; ++i)
            #pragma unroll
            for (int j = 0; j < 4; ++j) ps[(ty*4 + i)*65 + tx*4 + j] = s[i][j];
        __syncthreads();
        for (int kk = 0; kk < 64; ++kk) {
            float pv[4], vv[4];
            #pragma unroll
            for (int i = 0; i < 4; ++i) pv[i] = ps[(ty*4 + i)*65 + kk];
            #pragma unroll
            for (int jj = 0; jj < 4; ++jj) vv[jj] = vs[kk*65 + tx*4 + jj];
            #pragma unroll
            for (int i = 0; i < 4; ++i)
                #pragma unroll
                for (int jj = 0; jj < 4; ++jj) acc[i][jj] += pv[i] * vv[jj];
        }
        __syncthreads();
    }
    #pragma unroll
    for (int i = 0; i < 4; ++i) {
        float inv = 1.f / l_i[i];
        int bt = b*TT + it*64 + ty*4 + i;
        #pragma unroll
        for (int jj = 0; jj < 4; ++jj)
            att[((size_t)bt*NN + n)*GD + tx*4 + jj] = acc[i][jj] * inv;
    }
}

// ---- fc: smlp[bt,n] = sum_o relu(mlp_fc[n] @ rms(xi+att*aps))^2.  grid (BT/64, NN). ----
__global__ __launch_bounds__(256) void k_fc2(const float* __restrict__ xi, const float* __restrict__ att,
        const float* __restrict__ aps, const float* __restrict__ mlp_fc, float* __restrict__ smlp,
        const float* __restrict__ depths, const int* __restrict__ ns, int t) {
    int n = blockIdx.y;
    if (step_weight(depths, ns, t, n) == 0.f) return;
    int bt0 = blockIdx.x * 64;
    __shared__ float ys[64*65], ws[64*65], sred[256];
    int tid = threadIdx.x, lane = tid & 63, wv = tid >> 6;
    for (int tr = 0; tr < 16; ++tr) {
        int row = wv*16 + tr, bt = bt0 + row;
        size_t base = ((size_t)bt*NN + n)*GD + lane;
        float xv = xi[base] + att[base] * aps[n*GD + lane];
        float ss = xv*xv;
        for (int o = 32; o > 0; o >>= 1) ss += __shfl_xor(ss, o);
        ys[row*65 + lane] = xv * rsqrtf(ss / (float)GD + EPS);
    }
    __syncthreads();
    float sp = 0.f;
    for (int c = 0; c < 4; ++c) {
        for (int i4 = tid; i4 < 1024; i4 += 256) {
            int oo = i4 >> 4, c4 = (i4 & 15) * 4;
            float4 f = *(const float4*)(mlp_fc + ((size_t)n*256 + c*64 + oo)*GD + c4);
            ws[oo*65 + c4+0] = f.x; ws[oo*65 + c4+1] = f.y; ws[oo*65 + c4+2] = f.z; ws[oo*65 + c4+3] = f.w;
        }
        __syncthreads();
        int r = lane;
        for (int j = 0; j < 16; ++j) {
            int oo = wv*16 + j;
            float a = 0.f;
            for (int g = 0; g < 64; ++g) a += ys[r*65 + g] * ws[oo*65 + g];
            float rr = fmaxf(a, 0.f);
            sp += rr*rr;
        }
        __syncthreads();
    }
    sred[tid] = sp;
    __syncthreads();
    if (tid < 64)
        smlp[(size_t)(bt0 + tid)*NN + n] = sred[tid] + sred[tid+64] + sred[tid+128] + sred[tid+192];
}

__global__ __launch_bounds__(256) void k_update(float* __restrict__ x, float* __restrict__ pcont,
                                                const float* __restrict__ att, const float* __restrict__ smlp,
                                                const float* __restrict__ aps, const float* __restrict__ mps,
                                                const float* __restrict__ router_w, const float* __restrict__ router_b,
                                                const float* __restrict__ depths, const int* __restrict__ ns, int t) {
    int bt = blockIdx.x, tid = threadIdx.x;
    __shared__ float we[NN];
    __shared__ float red[4];
    if (tid < NN) we[tid] = step_weight(depths, ns, t, tid);
    __syncthreads();
    float pc = pcont[bt];
    float dot = 0.f;
    #pragma unroll
    for (int h = 0; h < 2; ++h) {
        int e = tid + h*256;
        int gq = e >> 6, gd = e & 63;
        float sum = 0.f;
        #pragma unroll
        for (int l = 0; l < LL; ++l) {
            int n = l*GG + gq;
            float w = we[n];
            if (w != 0.f) {
                sum += (att[((size_t)bt*NN + n)*GD + gd] * aps[n*GD + gd]
                        + smlp[bt*NN + n] * mps[n*GD + gd]) * w;
            }
        }
        float xv = x[bt*EE + e] + sum * pc;
        x[bt*EE + e] = xv;
        dot += xv * router_w[e];
    }
    for (int o = 32; o > 0; o >>= 1) dot += __shfl_xor(dot, o);
    if ((tid & 63) == 0) red[tid >> 6] = dot;
    __syncthreads();
    if (tid == 0) {
        float z = red[0]+red[1]+red[2]+red[3] + router_b[0];
        float ph = 1.f / (1.f + expf(-z));
        pcont[bt] = pc * (1.f - ph);
    }
}

__global__ void k_rmsconv(const float* __restrict__ x, __hip_bfloat16* __restrict__ ybf) {
    int bt = blockIdx.x, tid = threadIdx.x;
    float v0 = x[bt*EE + tid], v1 = x[bt*EE + tid + 256];
    __shared__ float red[4];
    float ss = v0*v0 + v1*v1;
    for (int o = 32; o > 0; o >>= 1) ss += __shfl_xor(ss, o);
    if ((tid & 63) == 0) red[tid >> 6] = ss;
    __syncthreads();
    float sc = rsqrtf((red[0]+red[1]+red[2]+red[3]) / (float)EE + EPS);
    ybf[bt*EE + tid]       = __float2bfloat16(v0 * sc);
    ybf[bt*EE + tid + 256] = __float2bfloat16(v1 * sc);
}

__global__ void k_convw(const float* __restrict__ w, __hip_bfloat16* __restrict__ wbf) {
    size_t i = ((size_t)blockIdx.x * blockDim.x + threadIdx.x) * 4;
    if (i >= (size_t)VV*EE) return;
    float4 f = *(const float4*)(w + i);
    wbf[i+0] = __float2bfloat16(f.x);
    wbf[i+1] = __float2bfloat16(f.y);
    wbf[i+2] = __float2bfloat16(f.z);
    wbf[i+3] = __float2bfloat16(f.w);
}

// out = 15*tanh((rms(x) @ W^T)/15), bf16 MFMA.  1D grid 1600 blocks, XCD-swizzled.
#define LM_BK 32
#define LM_PAD 48
__global__ __launch_bounds__(256) void k_lmhead(const __hip_bfloat16* __restrict__ ybf,
                                                const __hip_bfloat16* __restrict__ wbf,
                                                float* __restrict__ out) {
    // swizzle: 4 bm-blocks of the same bn land on the same XCD (id % 8 equal)
    int id = blockIdx.x;
    int bnLow = id & 7;
    int rest = id >> 3;
    int bm = rest & 3;
    int bnHigh = rest >> 2;
    int bn = bnHigh*8 + bnLow;
    if (bn >= (VV + 127)/128) return;

    __shared__ __align__(16) __hip_bfloat16 As[128][LM_PAD];
    __shared__ __align__(16) __hip_bfloat16 Bs[128][LM_PAD];
    int tid = threadIdx.x;
    int wave = tid >> 6, lane = tid & 63;
    int wr = wave >> 1, wc = wave & 1;
    int quad = lane >> 4, l16 = lane & 15;
    floatx4 acc[4][4];
    #pragma unroll
    for (int mt = 0; mt < 4; ++mt)
        #pragma unroll
        for (int nt = 0; nt < 4; ++nt)
            acc[mt][nt] = (floatx4){0.f, 0.f, 0.f, 0.f};

    for (int k0 = 0; k0 < EE; k0 += LM_BK) {
        for (int c = tid; c < 512; c += 256) {
            int row = c >> 2, koff = (c & 3) * 8;
            uint4 val = *(const uint4*)(ybf + ((size_t)(bm*128 + row)*EE + k0 + koff));
            *(uint4*)(&As[row][koff]) = val;
        }
        for (int c = tid; c < 512; c += 256) {
            int row = c >> 2, koff = (c & 3) * 8;
            int vrow = bn*128 + row;
            if (vrow >= VV) vrow = VV - 1;
            uint4 val = *(const uint4*)(wbf + ((size_t)vrow*EE + k0 + koff));
            *(uint4*)(&Bs[row][koff]) = val;
        }
        __syncthreads();
        short8 af[4], bf[4];
        #pragma unroll
        for (int mt = 0; mt < 4; ++mt)
            af[mt] = *(const short8*)(&As[wr*64 + mt*16 + l16][quad*8]);
        #pragma unroll
        for (int nt = 0; nt < 4; ++nt)
            bf[nt] = *(const short8*)(&Bs[wc*64 + nt*16 + l16][quad*8]);
        #pragma unroll
        for (int mt = 0; mt < 4; ++mt)
            #pragma unroll
            for (int nt = 0; nt < 4; ++nt)
                acc[mt][nt] = __builtin_amdgcn_mfma_f32_16x16x32_bf16(af[mt], bf[nt], acc[mt][nt], 0, 0, 0);
        __syncthreads();
    }
    #pragma unroll
    for (int mt = 0; mt < 4; ++mt) {
        int gm = bm*128 + wr*64 + mt*16 + quad*4;
        #pragma unroll
        for (int nt = 0; nt < 4; ++nt) {
            int gn = bn*128 + wc*64 + nt*16 + l16;
            if (gn < VV) {
                #pragma unroll
                for (int r = 0; r < 4; ++r) {
                    float lv = acc[mt][nt][r];
                    out[(size_t)(gm + r)*VV + gn] = 15.f * tanhf(lv * (1.f/15.f));
                }
            }
        }
    }
}

extern "C" void kernel_launch(void* const* d_in, const int* in_sizes, int n_in,
                              void* d_out, int out_size, void* d_ws, size_t ws_size,
                              hipStream_t stream) {
    (void)in_sizes; (void)n_in; (void)out_size; (void)ws_size;
    const int*   idx       = (const int*)d_in[0];
    const int*   nsteps    = (const int*)d_in[1];
    const float* wte       = (const float*)d_in[2];
    const float* adapters  = (const float*)d_in[3];
    const float* qkv_w     = (const float*)d_in[4];
    const float* attn_proj = (const float*)d_in[5];
    const float* mlp_fc    = (const float*)d_in[6];
    const float* mlp_proj  = (const float*)d_in[7];
    const float* dep       = (const float*)d_in[8];
    const float* router_w  = (const float*)d_in[9];
    const float* router_b  = (const float*)d_in[10];
    const float* lm_head   = (const float*)d_in[11];
    float* out = (float*)d_out;
    float* ws  = (float*)d_ws;

    float* depths = ws + OFF_DEPTHS;
    float* aps    = ws + OFF_APS;
    float* mps    = ws + OFF_MPS;
    float* ctab   = ws + OFF_COS;
    float* stab   = ws + OFF_SIN;
    float* x      = ws + OFF_X;
    float* pcont  = ws + OFF_PCONT;
    float* smlp   = ws + OFF_SMLP;
    float* xi     = ws + OFF_XI;
    float* q      = ws + OFF_Q;
    float* k      = ws + OFF_K;
    float* v      = ws + OFF_V;
    float* att    = ws + OFF_ATT;
    __hip_bfloat16* wbf = (__hip_bfloat16*)(ws + OFF_WBF);
    __hip_bfloat16* ybf = (__hip_bfloat16*)(ws + OFF_YBF);

    k_prep<<<1, 64, 0, stream>>>(dep, depths);
    k_sums<<<(NN*GD + 255)/256, 256, 0, stream>>>(attn_proj, mlp_proj, aps, mps);
    k_rope_table<<<(TT*D2 + 255)/256, 256, 0, stream>>>(ctab, stab);
    k_embed<<<BT, 256, 0, stream>>>(idx, wte, x, pcont);

    for (int t = 0; t < 8; ++t) {
        k_xi_qkv<<<dim3(BT/64, NN), 256, 0, stream>>>(x, adapters, qkv_w, xi, q, k, v,
                                                      ctab, stab, depths, nsteps, t);
        k_attn<<<dim3(4, BB, NN), 256, 0, stream>>>(q, k, v, att, depths, nsteps, t);
        k_fc2<<<dim3(BT/64, NN), 256, 0, stream>>>(xi, att, aps, mlp_fc, smlp, depths, nsteps, t);
        k_update<<<BT, 256, 0, stream>>>(x, pcont, att, smlp, aps, mps, router_w, router_b, depths, nsteps, t);
    }

    k_rmsconv<<<BT, 256, 0, stream>>>(x, ybf);
    k_convw<<<((VV*EE)/4 + 255)/256, 256, 0, stream>>>(lm_head, wbf);
    k_lmhead<<<1600, 256, 0, stream>>>(ybf, wbf, out);
}

// Round 3
// 776.427 us; speedup vs baseline: 3.8526x; 2.9810x over previous
//
#include <hip/hip_runtime.h>
#include <hip/hip_bf16.h>
#include <math.h>

// Problem constants (from reference)
#define BB 2
#define TT 256
#define BT 512      // B*T
#define EE 512
#define GG 8
#define GD 64
#define LL 8
#define NN 64
#define VV 50257
#define D2 32
#define EPS 1.1920928955078125e-07f
#define S72 72      // LDS row stride in bf16 (144 B -> 2-way bank alias = free)

typedef __attribute__((ext_vector_type(4))) float floatx4;
typedef __attribute__((ext_vector_type(8))) short short8;

// ---------------- workspace layout (float offsets) ----------------
#define OFF_DEPTHS   0
#define OFF_APS      64
#define OFF_MPS      (OFF_APS + NN*GD)            // 4160
#define OFF_COS      (OFF_MPS + NN*GD)            // 8256
#define OFF_SIN      (OFF_COS + TT*D2)            // 16448
#define OFF_X        (OFF_SIN + TT*D2)            // 24640
#define OFF_PCONT    (OFF_X + BT*EE)              // 286784
#define OFF_SMLP     (OFF_PCONT + BT)             // 287296
#define OFF_YBF      (OFF_SMLP + BT*NN)           // 320064 (bf16 BT*EE)
// step-loop region (dead after loop; wbf overlays it)
#define OFF_STEP     (OFF_YBF + (BT*EE)/2)        // 451136
#define OFF_XI       OFF_STEP                     // fp32 BT*NN*GD
#define OFF_ATT      (OFF_XI + BT*NN*GD)          // fp32
#define OFF_XBF      (OFF_ATT + BT*NN*GD)         // bf16 BT*EE
#define OFF_QB       (OFF_XBF + (BT*EE)/2)        // bf16 BT*NN*GD
#define OFF_KB       (OFF_QB + (BT*NN*GD)/2)
#define OFF_VTB      (OFF_KB + (BT*NN*GD)/2)      // bf16, transposed [b][n][g][t]
#define OFF_ABF      (OFF_VTB + (BT*NN*GD)/2)     // bf16 NN*GD*EE
#define OFF_QWBF     (OFF_ABF + (NN*GD*EE)/2)     // bf16 NN*192*GD
#define OFF_FWBF     (OFF_QWBF + (NN*192*GD)/2)   // bf16 NN*256*GD
// after step loop: wbf overlays OFF_STEP..
#define OFF_WBF      OFF_STEP                     // bf16 VV*EE

__device__ __forceinline__ float step_weight(const float* depths, const int* ns, int t, int n) {
    float td = (float)t * (8.0f / (float)ns[0]);
    float wa = expf(-fabsf(depths[n] - td));
    return (wa > 0.15f) ? wa : 0.0f;
}

__global__ void k_prep(const float* __restrict__ dep, float* __restrict__ depths) {
    __shared__ float cur[NN], nxt[NN];
    int i = threadIdx.x;
    if (i < NN) cur[i] = 0.f;
    __syncthreads();
    for (int it = 0; it < LL; ++it) {
        if (i < NN) {
            float acc = 0.f;
            for (int m = 0; m < NN; ++m) acc += fmaxf(dep[i*NN + m], 0.f) * (cur[m] + 1.f);
            nxt[i] = acc;
        }
        __syncthreads();
        if (i < NN) cur[i] = nxt[i];
        __syncthreads();
    }
    if (i < NN) depths[i] = cur[i];
}

__global__ void k_sums(const float* __restrict__ attn_proj, const float* __restrict__ mlp_proj,
                       float* __restrict__ aps, float* __restrict__ mps) {
    int i = blockIdx.x * blockDim.x + threadIdx.x;
    if (i >= NN*GD) return;
    float a = 0.f;
    const float* ap = attn_proj + (size_t)i * GD;
    for (int k = 0; k < GD; ++k) a += ap[k];
    aps[i] = a;
    float m = 0.f;
    const float* mp = mlp_proj + (size_t)i * 4 * GD;
    for (int k = 0; k < 4*GD; ++k) m += mp[k];
    mps[i] = m;
}

__global__ void k_rope_table(float* __restrict__ ctab, float* __restrict__ stab) {
    int i = blockIdx.x * blockDim.x + threadIdx.x;
    if (i >= TT*D2) return;
    int pos = i / D2, f = i % D2;
    double inv = pow(10000.0, -((double)(2*f)) / (double)GD);
    double ang = (double)pos * inv;
    ctab[i] = (float)cos(ang);
    stab[i] = (float)sin(ang);
}

// generic f32 -> bf16 (4 elems/thread)
__global__ void k_cvt(const float* __restrict__ src, __hip_bfloat16* __restrict__ dst, int n4) {
    int i = blockIdx.x * blockDim.x + threadIdx.x;
    if (i >= n4) return;
    float4 f = ((const float4*)src)[i];
    __hip_bfloat16* d = dst + (size_t)i*4;
    d[0] = __float2bfloat16(f.x);
    d[1] = __float2bfloat16(f.y);
    d[2] = __float2bfloat16(f.z);
    d[3] = __float2bfloat16(f.w);
}

__global__ void k_embed(const int* __restrict__ idx, const float* __restrict__ wte,
                        float* __restrict__ x, __hip_bfloat16* __restrict__ xbf,
                        float* __restrict__ pcont) {
    int bt = blockIdx.x;
    int tid = threadIdx.x;
    const float* src = wte + (size_t)idx[bt] * EE;
    float v0 = src[tid], v1 = src[tid + 256];
    __shared__ float red[4];
    float ss = v0*v0 + v1*v1;
    for (int o = 32; o > 0; o >>= 1) ss += __shfl_xor(ss, o);
    if ((tid & 63) == 0) red[tid >> 6] = ss;
    __syncthreads();
    float sc = rsqrtf((red[0]+red[1]+red[2]+red[3]) / (float)EE + EPS);
    float a = v0 * sc, b = v1 * sc;
    x[bt*EE + tid]       = a;
    x[bt*EE + tid + 256] = b;
    xbf[bt*EE + tid]       = __float2bfloat16(a);
    xbf[bt*EE + tid + 256] = __float2bfloat16(b);
    if (tid == 0) pcont[bt] = 1.f;
}

// ---- Fused xi + qkv + rope + rms, bf16 MFMA.  grid (BT/64, NN), 256 thr. ----
__global__ __launch_bounds__(256) void k_xi_qkv(const __hip_bfloat16* __restrict__ xbf,
        const __hip_bfloat16* __restrict__ abf, const __hip_bfloat16* __restrict__ qwbf,
        const float* __restrict__ x, float* __restrict__ xi,
        __hip_bfloat16* __restrict__ qb, __hip_bfloat16* __restrict__ kb,
        __hip_bfloat16* __restrict__ vtb,
        const float* __restrict__ ctab, const float* __restrict__ stab,
        const float* __restrict__ depths, const int* __restrict__ ns, int t) {
    int n = blockIdx.y;
    if (step_weight(depths, ns, t, n) == 0.f) return;
    int bt0 = blockIdx.x * 64;
    __shared__ __align__(16) __hip_bfloat16 As[64*S72];
    __shared__ __align__(16) __hip_bfloat16 Bs[64*S72];
    __shared__ __align__(16) __hip_bfloat16 xis[64*S72];
    __shared__ float obuf[64*65];
    int tid = threadIdx.x;
    int wave = tid >> 6, lane = tid & 63;
    int wr = wave >> 1, wc = wave & 1;
    int quad = lane >> 4, l16 = lane & 15;

    // ---- phase 1: xi = xbf @ abf[n]^T  (64 tok x 64 g, K=512) ----
    floatx4 acc[2][2];
    #pragma unroll
    for (int mt = 0; mt < 2; ++mt)
        #pragma unroll
        for (int nt = 0; nt < 2; ++nt) acc[mt][nt] = (floatx4){0.f,0.f,0.f,0.f};
    for (int k0 = 0; k0 < EE; k0 += 64) {
        for (int i = tid; i < 512; i += 256) {
            int r = i >> 3, c8 = (i & 7) * 8;
            *(uint4*)(&As[r*S72 + c8]) = *(const uint4*)(&xbf[(size_t)(bt0 + r)*EE + k0 + c8]);
            *(uint4*)(&Bs[r*S72 + c8]) = *(const uint4*)(&abf[((size_t)n*GD + r)*EE + k0 + c8]);
        }
        __syncthreads();
        #pragma unroll
        for (int ks = 0; ks < 2; ++ks) {
            short8 af[2], bf[2];
            #pragma unroll
            for (int mt = 0; mt < 2; ++mt)
                af[mt] = *(const short8*)(&As[(wr*32 + mt*16 + l16)*S72 + ks*32 + quad*8]);
            #pragma unroll
            for (int nt = 0; nt < 2; ++nt)
                bf[nt] = *(const short8*)(&Bs[(wc*32 + nt*16 + l16)*S72 + ks*32 + quad*8]);
            #pragma unroll
            for (int mt = 0; mt < 2; ++mt)
                #pragma unroll
                for (int nt = 0; nt < 2; ++nt)
                    acc[mt][nt] = __builtin_amdgcn_mfma_f32_16x16x32_bf16(af[mt], bf[nt], acc[mt][nt], 0, 0, 0);
        }
        __syncthreads();
    }
    int gofs = (n & (GG-1)) * GD;
    #pragma unroll
    for (int mt = 0; mt < 2; ++mt) {
        #pragma unroll
        for (int nt = 0; nt < 2; ++nt) {
            int col = wc*32 + nt*16 + l16;
            #pragma unroll
            for (int r = 0; r < 4; ++r) {
                int token = wr*32 + mt*16 + quad*4 + r;
                int bt = bt0 + token;
                float val = acc[mt][nt][r] + x[(size_t)bt*EE + gofs + col];
                xi[((size_t)bt*NN + n)*GD + col] = val;
                xis[token*S72 + col] = __float2bfloat16(val);
            }
        }
    }
    __syncthreads();

    // ---- phase 2: qkv = xis @ qkv_w[n]^T (per c: 64 tok x 64 out, K=64) ----
    const __hip_bfloat16* wbase = qwbf + (size_t)n * 192 * GD;
    int b = bt0 >> 8;           // batch index
    int t0 = bt0 & (TT - 1);    // position of first token in tile
    for (int c = 0; c < 3; ++c) {
        for (int i = tid; i < 512; i += 256) {
            int r = i >> 3, c8 = (i & 7) * 8;
            *(uint4*)(&Bs[r*S72 + c8]) = *(const uint4*)(&wbase[(size_t)(c*64 + r)*GD + c8]);
        }
        __syncthreads();
        floatx4 oacc[2][2];
        #pragma unroll
        for (int mt = 0; mt < 2; ++mt)
            #pragma unroll
            for (int nt = 0; nt < 2; ++nt) oacc[mt][nt] = (floatx4){0.f,0.f,0.f,0.f};
        #pragma unroll
        for (int ks = 0; ks < 2; ++ks) {
            short8 af[2], bf[2];
            #pragma unroll
            for (int mt = 0; mt < 2; ++mt)
                af[mt] = *(const short8*)(&xis[(wr*32 + mt*16 + l16)*S72 + ks*32 + quad*8]);
            #pragma unroll
            for (int nt = 0; nt < 2; ++nt)
                bf[nt] = *(const short8*)(&Bs[(wc*32 + nt*16 + l16)*S72 + ks*32 + quad*8]);
            #pragma unroll
            for (int mt = 0; mt < 2; ++mt)
                #pragma unroll
                for (int nt = 0; nt < 2; ++nt)
                    oacc[mt][nt] = __builtin_amdgcn_mfma_f32_16x16x32_bf16(af[mt], bf[nt], oacc[mt][nt], 0, 0, 0);
        }
        #pragma unroll
        for (int mt = 0; mt < 2; ++mt)
            #pragma unroll
            for (int nt = 0; nt < 2; ++nt)
                #pragma unroll
                for (int r = 0; r < 4; ++r)
                    obuf[(wr*32 + mt*16 + quad*4 + r)*65 + wc*32 + nt*16 + l16] = oacc[mt][nt][r];
        __syncthreads();
        if (c < 2) {
            // rope + rms per token-row, write bf16
            __hip_bfloat16* dst = (c == 0) ? qb : kb;
            for (int tr = 0; tr < 16; ++tr) {
                int row = wave*16 + tr, bt = bt0 + row;
                float val = obuf[row*65 + lane];
                int pos = bt & (TT - 1);
                float pair = __shfl_xor(val, 32);
                int fi = lane & 31;
                float cc = ctab[pos*D2 + fi], sn = stab[pos*D2 + fi];
                float nv = (lane < 32) ? (val*cc + pair*sn) : (val*cc - pair*sn);
                float ss = nv*nv;
                for (int o = 32; o > 0; o >>= 1) ss += __shfl_xor(ss, o);
                float outv = nv * rsqrtf(ss / (float)GD + EPS);
                dst[((size_t)bt*NN + n)*GD + lane] = __float2bfloat16(outv);
            }
        } else {
            // v: read obuf transposed (conflict-free), write coalesced to vtb[b][n][g][t]
            for (int tr = 0; tr < 16; ++tr) {
                int g = wave*16 + tr;
                float vv = obuf[lane*65 + g];
                vtb[(((size_t)(b*NN + n))*GD + g)*TT + t0 + lane] = __float2bfloat16(vv);
            }
        }
        __syncthreads();
    }
}

// ---- Flash attention, bf16 MFMA.  grid (4, B, NN), 256 thr (4 waves, 16 rows each). ----
__global__ __launch_bounds__(256) void k_attn(const __hip_bfloat16* __restrict__ qb,
        const __hip_bfloat16* __restrict__ kb, const __hip_bfloat16* __restrict__ vtb,
        float* __restrict__ att,
        const float* __restrict__ depths, const int* __restrict__ ns, int t) {
    int it = blockIdx.x, b = blockIdx.y, n = blockIdx.z;
    if (step_weight(depths, ns, t, n) == 0.f) return;
    __shared__ __align__(16) __hip_bfloat16 qs[64*S72];
    __shared__ __align__(16) __hip_bfloat16 ksm[64*S72];
    __shared__ __align__(16) __hip_bfloat16 vs[64*S72];
    __shared__ __align__(16) __hip_bfloat16 ps[64*S72];
    int tid = threadIdx.x;
    int wave = tid >> 6, lane = tid & 63;
    int quad = lane >> 4, l16 = lane & 15;
    for (int i = tid; i < 512; i += 256) {
        int r = i >> 3, c8 = (i & 7) * 8;
        *(uint4*)(&qs[r*S72 + c8]) = *(const uint4*)(&qb[(((size_t)(b*TT + it*64 + r))*NN + n)*GD + c8]);
    }
    floatx4 oacc[4];
    float m_i[4], l_i[4];
    #pragma unroll
    for (int nt = 0; nt < 4; ++nt) oacc[nt] = (floatx4){0.f,0.f,0.f,0.f};
    #pragma unroll
    for (int r = 0; r < 4; ++r) { m_i[r] = -INFINITY; l_i[r] = 0.f; }
    __syncthreads();
    for (int ct = 0; ct <= it; ++ct) {
        for (int i = tid; i < 512; i += 256) {
            int r = i >> 3, c8 = (i & 7) * 8;
            *(uint4*)(&ksm[r*S72 + c8]) = *(const uint4*)(&kb[(((size_t)(b*TT + ct*64 + r))*NN + n)*GD + c8]);
            *(uint4*)(&vs[r*S72 + c8])  = *(const uint4*)(&vtb[(((size_t)(b*NN + n))*GD + r)*TT + ct*64 + c8]);
        }
        __syncthreads();
        // S = Q K^T : rows = wave*16.., cols = full 64
        floatx4 s[4];
        #pragma unroll
        for (int nt = 0; nt < 4; ++nt) s[nt] = (floatx4){0.f,0.f,0.f,0.f};
        #pragma unroll
        for (int ks = 0; ks < 2; ++ks) {
            short8 af = *(const short8*)(&qs[(wave*16 + l16)*S72 + ks*32 + quad*8]);
            #pragma unroll
            for (int nt = 0; nt < 4; ++nt) {
                short8 bf = *(const short8*)(&ksm[(nt*16 + l16)*S72 + ks*32 + quad*8]);
                s[nt] = __builtin_amdgcn_mfma_f32_16x16x32_bf16(af, bf, s[nt], 0, 0, 0);
            }
        }
        // online softmax per row (row = wave*16 + quad*4 + r)
        #pragma unroll
        for (int r = 0; r < 4; ++r) {
            int rowg = it*64 + wave*16 + quad*4 + r;
            float mx = -INFINITY;
            #pragma unroll
            for (int nt = 0; nt < 4; ++nt) {
                int colg = ct*64 + nt*16 + l16;
                float sv = (colg <= rowg) ? s[nt][r] * 0.125f : -INFINITY;
                s[nt][r] = sv;
                mx = fmaxf(mx, sv);
            }
            for (int o = 8; o > 0; o >>= 1) mx = fmaxf(mx, __shfl_xor(mx, o));
            float mnew = fmaxf(m_i[r], mx);
            float alpha = expf(m_i[r] - mnew);
            float rs = 0.f;
            #pragma unroll
            for (int nt = 0; nt < 4; ++nt) {
                float p = expf(s[nt][r] - mnew);
                s[nt][r] = p;
                rs += p;
            }
            for (int o = 8; o > 0; o >>= 1) rs += __shfl_xor(rs, o);
            l_i[r] = l_i[r]*alpha + rs;
            m_i[r] = mnew;
            #pragma unroll
            for (int nt = 0; nt < 4; ++nt) oacc[nt][r] *= alpha;
        }
        // P -> LDS (A-layout rows = q-token)
        #pragma unroll
        for (int nt = 0; nt < 4; ++nt)
            #pragma unroll
            for (int r = 0; r < 4; ++r)
                ps[(wave*16 + quad*4 + r)*S72 + nt*16 + l16] = __float2bfloat16(s[nt][r]);
        __syncthreads();
        // O += P V : B-operand rows = g (vtb transposed), k = ct-token
        #pragma unroll
        for (int ks = 0; ks < 2; ++ks) {
            short8 af = *(const short8*)(&ps[(wave*16 + l16)*S72 + ks*32 + quad*8]);
            #pragma unroll
            for (int nt = 0; nt < 4; ++nt) {
                short8 bf = *(const short8*)(&vs[(nt*16 + l16)*S72 + ks*32 + quad*8]);
                oacc[nt] = __builtin_amdgcn_mfma_f32_16x16x32_bf16(af, bf, oacc[nt], 0, 0, 0);
            }
        }
        __syncthreads();
    }
    #pragma unroll
    for (int r = 0; r < 4; ++r) {
        float inv = 1.f / l_i[r];
        int token = it*64 + wave*16 + quad*4 + r;
        #pragma unroll
        for (int nt = 0; nt < 4; ++nt)
            att[((size_t)(b*TT + token)*NN + n)*GD + nt*16 + l16] = oacc[nt][r] * inv;
    }
}

// ---- fc: smlp = sum_o relu(mlp_fc[n] @ rms(xi+att*aps))^2, bf16 MFMA.  grid (BT/64, NN). ----
__global__ __launch_bounds__(256) void k_fc2(const float* __restrict__ xi, const float* __restrict__ att,
        const float* __restrict__ aps, const __hip_bfloat16* __restrict__ fwbf, float* __restrict__ smlp,
        const float* __restrict__ depths, const int* __restrict__ ns, int t) {
    int n = blockIdx.y;
    if (step_weight(depths, ns, t, n) == 0.f) return;
    int bt0 = blockIdx.x * 64;
    __shared__ __align__(16) __hip_bfloat16 ys[64*S72];
    __shared__ __align__(16) __hip_bfloat16 ws[64*S72];
    __shared__ float sred[64];
    int tid = threadIdx.x;
    int wave = tid >> 6, lane = tid & 63;
    int quad = lane >> 4, l16 = lane & 15;
    for (int tr = 0; tr < 16; ++tr) {
        int row = wave*16 + tr, bt = bt0 + row;
        size_t base = ((size_t)bt*NN + n)*GD + lane;
        float xv = xi[base] + att[base] * aps[n*GD + lane];
        float ss = xv*xv;
        for (int o = 32; o > 0; o >>= 1) ss += __shfl_xor(ss, o);
        ys[row*S72 + lane] = __float2bfloat16(xv * rsqrtf(ss / (float)GD + EPS));
    }
    __syncthreads();
    float rowacc[4] = {0.f, 0.f, 0.f, 0.f};
    for (int c = 0; c < 4; ++c) {
        for (int i = tid; i < 512; i += 256) {
            int r = i >> 3, c8 = (i & 7) * 8;
            *(uint4*)(&ws[r*S72 + c8]) = *(const uint4*)(&fwbf[((size_t)n*256 + c*64 + r)*GD + c8]);
        }
        __syncthreads();
        floatx4 s[4];
        #pragma unroll
        for (int nt = 0; nt < 4; ++nt) s[nt] = (floatx4){0.f,0.f,0.f,0.f};
        #pragma unroll
        for (int ks = 0; ks < 2; ++ks) {
            short8 af = *(const short8*)(&ys[(wave*16 + l16)*S72 + ks*32 + quad*8]);
            #pragma unroll
            for (int nt = 0; nt < 4; ++nt) {
                short8 bf = *(const short8*)(&ws[(nt*16 + l16)*S72 + ks*32 + quad*8]);
                s[nt] = __builtin_amdgcn_mfma_f32_16x16x32_bf16(af, bf, s[nt], 0, 0, 0);
            }
        }
        #pragma unroll
        for (int nt = 0; nt < 4; ++nt)
            #pragma unroll
            for (int r = 0; r < 4; ++r) {
                float rr = fmaxf(s[nt][r], 0.f);
                rowacc[r] += rr*rr;
            }
        __syncthreads();
    }
    #pragma unroll
    for (int r = 0; r < 4; ++r) {
        for (int o = 8; o > 0; o >>= 1) rowacc[r] += __shfl_xor(rowacc[r], o);
        if (l16 == 0) sred[wave*16 + quad*4 + r] = rowacc[r];
    }
    __syncthreads();
    if (tid < 64) smlp[(size_t)(bt0 + tid)*NN + n] = sred[tid];
}

__global__ __launch_bounds__(256) void k_update(float* __restrict__ x, __hip_bfloat16* __restrict__ xbf,
                                                float* __restrict__ pcont,
                                                const float* __restrict__ att, const float* __restrict__ smlp,
                                                const float* __restrict__ aps, const float* __restrict__ mps,
                                                const float* __restrict__ router_w, const float* __restrict__ router_b,
                                                const float* __restrict__ depths, const int* __restrict__ ns, int t) {
    int bt = blockIdx.x, tid = threadIdx.x;
    __shared__ float we[NN];
    __shared__ float red[4];
    if (tid < NN) we[tid] = step_weight(depths, ns, t, tid);
    __syncthreads();
    float pc = pcont[bt];
    float dot = 0.f;
    #pragma unroll
    for (int h = 0; h < 2; ++h) {
        int e = tid + h*256;
        int gq = e >> 6, gd = e & 63;
        float sum = 0.f;
        #pragma unroll
        for (int l = 0; l < LL; ++l) {
            int n = l*GG + gq;
            float w = we[n];
            if (w != 0.f) {
                sum += (att[((size_t)bt*NN + n)*GD + gd] * aps[n*GD + gd]
                        + smlp[bt*NN + n] * mps[n*GD + gd]) * w;
            }
        }
        float xv = x[bt*EE + e] + sum * pc;
        x[bt*EE + e] = xv;
        xbf[bt*EE + e] = __float2bfloat16(xv);
        dot += xv * router_w[e];
    }
    for (int o = 32; o > 0; o >>= 1) dot += __shfl_xor(dot, o);
    if ((tid & 63) == 0) red[tid >> 6] = dot;
    __syncthreads();
    if (tid == 0) {
        float z = red[0]+red[1]+red[2]+red[3] + router_b[0];
        float ph = 1.f / (1.f + expf(-z));
        pcont[bt] = pc * (1.f - ph);
    }
}

__global__ void k_rmsconv(const float* __restrict__ x, __hip_bfloat16* __restrict__ ybf) {
    int bt = blockIdx.x, tid = threadIdx.x;
    float v0 = x[bt*EE + tid], v1 = x[bt*EE + tid + 256];
    __shared__ float red[4];
    float ss = v0*v0 + v1*v1;
    for (int o = 32; o > 0; o >>= 1) ss += __shfl_xor(ss, o);
    if ((tid & 63) == 0) red[tid >> 6] = ss;
    __syncthreads();
    float sc = rsqrtf((red[0]+red[1]+red[2]+red[3]) / (float)EE + EPS);
    ybf[bt*EE + tid]       = __float2bfloat16(v0 * sc);
    ybf[bt*EE + tid + 256] = __float2bfloat16(v1 * sc);
}

// out = 15*tanh((rms(x) @ W^T)/15), bf16 MFMA.  1D grid 1600 blocks, XCD-swizzled.
#define LM_BK 32
#define LM_PAD 48
__global__ __launch_bounds__(256) void k_lmhead(const __hip_bfloat16* __restrict__ ybf,
                                                const __hip_bfloat16* __restrict__ wbf,
                                                float* __restrict__ out) {
    int id = blockIdx.x;
    int bnLow = id & 7;
    int rest = id >> 3;
    int bm = rest & 3;
    int bnHigh = rest >> 2;
    int bn = bnHigh*8 + bnLow;
    if (bn >= (VV + 127)/128) return;

    __shared__ __align__(16) __hip_bfloat16 As[128][LM_PAD];
    __shared__ __align__(16) __hip_bfloat16 Bs[128][LM_PAD];
    int tid = threadIdx.x;
    int wave = tid >> 6, lane = tid & 63;
    int wr = wave >> 1, wc = wave & 1;
    int quad = lane >> 4, l16 = lane & 15;
    floatx4 acc[4][4];
    #pragma unroll
    for (int mt = 0; mt < 4; ++mt)
        #pragma unroll
        for (int nt = 0; nt < 4; ++nt)
            acc[mt][nt] = (floatx4){0.f, 0.f, 0.f, 0.f};

    for (int k0 = 0; k0 < EE; k0 += LM_BK) {
        for (int c = tid; c < 512; c += 256) {
            int row = c >> 2, koff = (c & 3) * 8;
            uint4 val = *(const uint4*)(ybf + ((size_t)(bm*128 + row)*EE + k0 + koff));
            *(uint4*)(&As[row][koff]) = val;
        }
        for (int c = tid; c < 512; c += 256) {
            int row = c >> 2, koff = (c & 3) * 8;
            int vrow = bn*128 + row;
            if (vrow >= VV) vrow = VV - 1;
            uint4 val = *(const uint4*)(wbf + ((size_t)vrow*EE + k0 + koff));
            *(uint4*)(&Bs[row][koff]) = val;
        }
        __syncthreads();
        short8 af[4], bf[4];
        #pragma unroll
        for (int mt = 0; mt < 4; ++mt)
            af[mt] = *(const short8*)(&As[wr*64 + mt*16 + l16][quad*8]);
        #pragma unroll
        for (int nt = 0; nt < 4; ++nt)
            bf[nt] = *(const short8*)(&Bs[wc*64 + nt*16 + l16][quad*8]);
        #pragma unroll
        for (int mt = 0; mt < 4; ++mt)
            #pragma unroll
            for (int nt = 0; nt < 4; ++nt)
                acc[mt][nt] = __builtin_amdgcn_mfma_f32_16x16x32_bf16(af[mt], bf[nt], acc[mt][nt], 0, 0, 0);
        __syncthreads();
    }
    #pragma unroll
    for (int mt = 0; mt < 4; ++mt) {
        int gm = bm*128 + wr*64 + mt*16 + quad*4;
        #pragma unroll
        for (int nt = 0; nt < 4; ++nt) {
            int gn = bn*128 + wc*64 + nt*16 + l16;
            if (gn < VV) {
                #pragma unroll
                for (int r = 0; r < 4; ++r) {
                    float lv = acc[mt][nt][r];
                    out[(size_t)(gm + r)*VV + gn] = 15.f * tanhf(lv * (1.f/15.f));
                }
            }
        }
    }
}

extern "C" void kernel_launch(void* const* d_in, const int* in_sizes, int n_in,
                              void* d_out, int out_size, void* d_ws, size_t ws_size,
                              hipStream_t stream) {
    (void)in_sizes; (void)n_in; (void)out_size; (void)ws_size;
    const int*   idx       = (const int*)d_in[0];
    const int*   nsteps    = (const int*)d_in[1];
    const float* wte       = (const float*)d_in[2];
    const float* adapters  = (const float*)d_in[3];
    const float* qkv_w     = (const float*)d_in[4];
    const float* attn_proj = (const float*)d_in[5];
    const float* mlp_fc    = (const float*)d_in[6];
    const float* mlp_proj  = (const float*)d_in[7];
    const float* dep       = (const float*)d_in[8];
    const float* router_w  = (const float*)d_in[9];
    const float* router_b  = (const float*)d_in[10];
    const float* lm_head   = (const float*)d_in[11];
    float* out = (float*)d_out;
    float* ws  = (float*)d_ws;

    float* depths = ws + OFF_DEPTHS;
    float* aps    = ws + OFF_APS;
    float* mps    = ws + OFF_MPS;
    float* ctab   = ws + OFF_COS;
    float* stab   = ws + OFF_SIN;
    float* x      = ws + OFF_X;
    float* pcont  = ws + OFF_PCONT;
    float* smlp   = ws + OFF_SMLP;
    float* xi     = ws + OFF_XI;
    float* att    = ws + OFF_ATT;
    __hip_bfloat16* xbf  = (__hip_bfloat16*)(ws + OFF_XBF);
    __hip_bfloat16* qb   = (__hip_bfloat16*)(ws + OFF_QB);
    __hip_bfloat16* kb   = (__hip_bfloat16*)(ws + OFF_KB);
    __hip_bfloat16* vtb  = (__hip_bfloat16*)(ws + OFF_VTB);
    __hip_bfloat16* abf  = (__hip_bfloat16*)(ws + OFF_ABF);
    __hip_bfloat16* qwbf = (__hip_bfloat16*)(ws + OFF_QWBF);
    __hip_bfloat16* fwbf = (__hip_bfloat16*)(ws + OFF_FWBF);
    __hip_bfloat16* wbf  = (__hip_bfloat16*)(ws + OFF_WBF);
    __hip_bfloat16* ybf  = (__hip_bfloat16*)(ws + OFF_YBF);

    k_prep<<<1, 64, 0, stream>>>(dep, depths);
    k_sums<<<(NN*GD + 255)/256, 256, 0, stream>>>(attn_proj, mlp_proj, aps, mps);
    k_rope_table<<<(TT*D2 + 255)/256, 256, 0, stream>>>(ctab, stab);
    k_cvt<<<(NN*GD*EE/4 + 255)/256, 256, 0, stream>>>(adapters, abf, NN*GD*EE/4);
    k_cvt<<<(NN*192*GD/4 + 255)/256, 256, 0, stream>>>(qkv_w, qwbf, NN*192*GD/4);
    k_cvt<<<(NN*256*GD/4 + 255)/256, 256, 0, stream>>>(mlp_fc, fwbf, NN*256*GD/4);
    k_embed<<<BT, 256, 0, stream>>>(idx, wte, x, xbf, pcont);

    for (int t = 0; t < 8; ++t) {
        k_xi_qkv<<<dim3(BT/64, NN), 256, 0, stream>>>(xbf, abf, qwbf, x, xi, qb, kb, vtb,
                                                      ctab, stab, depths, nsteps, t);
        k_attn<<<dim3(4, BB, NN), 256, 0, stream>>>(qb, kb, vtb, att, depths, nsteps, t);
        k_fc2<<<dim3(BT/64, NN), 256, 0, stream>>>(xi, att, aps, fwbf, smlp, depths, nsteps, t);
        k_update<<<BT, 256, 0, stream>>>(x, xbf, pcont, att, smlp, aps, mps,
                                         router_w, router_b, depths, nsteps, t);
    }

    k_rmsconv<<<BT, 256, 0, stream>>>(x, ybf);
    k_cvt<<<((VV*EE)/4 + 255)/256, 256, 0, stream>>>(lm_head, wbf, (VV*EE)/4);
    k_lmhead<<<1600, 256, 0, stream>>>(ybf, wbf, out);
}